// Round 5
// baseline (16361.143 us; speedup 1.0000x reference)
//
#include <hip/hip_runtime.h>

#define SEQ    1000
#define BATCH  256
#define HID    256
#define NL     10
#define G4H    1024                    // 4*HID
#define WELT   (NL * G4H * HID)        // 2,621,440 elements per weight tensor
#define BH     (BATCH * HID)           // 65,536
#define NBLK   160
#define DSTR   32                      // done-flag stride in uints (128 B)

typedef __bf16 bf16x8 __attribute__((ext_vector_type(8)));
typedef float  f32x4  __attribute__((ext_vector_type(4)));

// ---- ws layout (bytes) ----
// 0          : wih_bf   (5,242,880)
// 5,242,880  : whh_bf   (5,242,880)
// 10,485,760 : biasc    (40,960)      fp32, b_ih+b_hh combined
// 10,526,720 : scb      (2,621,440)   bf16 h-state, [NL][2(parity)][B][H]
// 13,148,160 : cbuf     (2,359,296)   bf16 layer handoff, [NL-1][2(parity)][B][H]
// 15,507,456 : done     (5,120)       per-(layer,btile) step counters, stride DSTR

__global__ __launch_bounds__(256) void lstm_prep(
    const float* __restrict__ Wih, const float* __restrict__ Whh,
    const float* __restrict__ bih, const float* __restrict__ bhh,
    __bf16* __restrict__ wih_bf, __bf16* __restrict__ whh_bf,
    float* __restrict__ biasc, __bf16* __restrict__ scb,
    unsigned int* __restrict__ done)
{
    const int i0 = blockIdx.x * blockDim.x + threadIdx.x;
    const int stride = gridDim.x * blockDim.x;
    for (int i = i0; i < WELT; i += stride) {
        wih_bf[i] = (__bf16)Wih[i];
        whh_bf[i] = (__bf16)Whh[i];
    }
    for (int i = i0; i < NL * G4H; i += stride) biasc[i] = bih[i] + bhh[i];
    for (int i = i0; i < NL * 2 * BH; i += stride) scb[i] = (__bf16)0.0f;
    if (i0 < NL * 4 * DSTR) done[i0] = 0u;
}

// relaxed agent-scope spin: no acquire, no cache maintenance (proven R3/R4)
__device__ __forceinline__ void spin_ge(const unsigned int* p, unsigned int tgt)
{
    while (__hip_atomic_load(p, __ATOMIC_RELAXED, __HIP_MEMORY_SCOPE_AGENT) < tgt)
        __builtin_amdgcn_s_sleep(2);
}
// cross-XCD 16B load: bypass L1+L2, read coherence point
__device__ __forceinline__ void ldg_coh(bf16x8& d, const __bf16* p)
{
    asm volatile("global_load_dwordx4 %0, %1, off sc0 sc1" : "=v"(d) : "v"(p));
}
// intra-XCD 16B load: bypass L1 only (hits local L2 where sibling's store landed)
__device__ __forceinline__ void ldg_l2(bf16x8& d, const __bf16* p)
{
    asm volatile("global_load_dwordx4 %0, %1, off sc0" : "=v"(d) : "v"(p));
}
// cross-XCD 2B store: write-through to coherence point (no L2 dirty line)
__device__ __forceinline__ void stg_coh_b16(__bf16* p, __bf16 v)
{
    asm volatile("global_store_short %0, %1, off sc0 sc1" :: "v"(p), "v"(v) : "memory");
}
__device__ __forceinline__ void wait_vm0()
{
    asm volatile("s_waitcnt vmcnt(0)" ::: "memory");
}
// fast sigmoid/tanh: v_exp_f32 is 2^x; v_rcp_f32 ~1ulp — error << bf16 rounding
#define LOG2E 1.44269504f
__device__ __forceinline__ float fsigmoid(float x)
{
    return __builtin_amdgcn_rcpf(1.0f + __builtin_amdgcn_exp2f(-x * LOG2E));
}
__device__ __forceinline__ float ftanh(float x)
{
    return 1.0f - 2.0f * __builtin_amdgcn_rcpf(1.0f + __builtin_amdgcn_exp2f(x * (2.0f * LOG2E)));
}

// -------- main persistent kernel --------
// Mapping (blk%8 = XCD, perf heuristic; h-exchange correctness relies on it via sc0 loads
// — proven over R3/R4):
//   blk < 128 : j = blk&7, tile = blk>>3
//   blk >=128 : j = 8+((blk&7)>>2), tile = ((blk&3)<<2)|((blk-128)>>3)
// tile: b0=(tile>>2)*64, h0=(tile&3)*64. Wave v owns h cols h0+v*16..+16.
// Both Wih and Whh tile slices live in VGPRs (256 regs) -> zero steady-state weight traffic.
__global__ __launch_bounds__(256, 1) void lstm_main(
    const float* __restrict__ x,
    const __bf16* __restrict__ wih_bf, const __bf16* __restrict__ whh_bf,
    const float* __restrict__ biasc,
    __bf16* __restrict__ scb, __bf16* __restrict__ cbuf,
    float* __restrict__ out, unsigned int* __restrict__ done)
{
    __shared__ __bf16 Alds[64][512];   // 64 KiB; 16B-chunk XOR swizzle

    const int blk  = blockIdx.x;
    int j, tile;
    if (blk < 128) { j = blk & 7; tile = blk >> 3; }
    else           { j = 8 + ((blk & 7) >> 2); tile = ((blk & 3) << 2) | ((blk - 128) >> 3); }
    const int bt   = tile >> 2;
    const int b0   = bt << 6;
    const int h0   = (tile & 3) << 6;
    const int tid  = threadIdx.x;
    const int v    = tid >> 6;
    const int lane = tid & 63;
    const int m    = lane & 15;
    const int q    = lane >> 4;
    const int hw   = h0 + v * 16 + m;

    unsigned int* done_self = done + (j * 4 + bt) * DSTR;
    unsigned int* done_prod = done + ((j - 1) * 4 + bt) * DSTR;
    unsigned int* done_cons = done + ((j + 1) * 4 + bt) * DSTR;

    float biasg[4];
    bf16x8 wfhh[8][4];                 // Whh fragments resident (128 VGPRs)
    bf16x8 wfih[8][4];                 // Wih fragments resident (128 VGPRs)
#pragma unroll
    for (int g = 0; g < 4; ++g) {
        const size_t row = (size_t)j * G4H + g * HID + hw;
        biasg[g] = biasc[(size_t)j * G4H + g * HID + hw];
        const __bf16* hh = whh_bf + row * HID + q * 8;
        const __bf16* ih = wih_bf + row * HID + q * 8;
#pragma unroll
        for (int ch = 0; ch < 8; ++ch) {
            wfhh[ch][g] = *(const bf16x8*)(hh + ch * 32);
            wfih[ch][g] = *(const bf16x8*)(ih + ch * 32);
        }
    }

    float c_state[4][4];
#pragma unroll
    for (int bs = 0; bs < 4; ++bs)
#pragma unroll
        for (int r = 0; r < 4; ++r) c_state[bs][r] = 0.0f;

    for (int t = 0; t < SEQ; ++t) {
        const int par = t & 1;
        const __bf16* hprev = scb + (size_t)(j * 2 + ((t + 1) & 1)) * BH;
        __bf16* hout = scb + (size_t)(j * 2 + par) * BH;

        // W2: own group finished t-1 (h ready, hout slot reusable)
        if (t >= 1) spin_ge(done_self, 4u * (unsigned)t);

        // stage h_prev into Alds hi half (intra-XCD, L1-bypass)
        {
            bf16x8 tmp[8];
#pragma unroll
            for (int i = 0; i < 8; ++i) {
                const int row = i * 8 + v * 2 + (lane >> 5);
                const int c32 = lane & 31;
                ldg_l2(tmp[i], hprev + (size_t)(b0 + row) * HID + c32 * 8);
            }
            wait_vm0();
#pragma unroll
            for (int i = 0; i < 8; ++i) {
                const int row = i * 8 + v * 2 + (lane >> 5);
                const int c32 = lane & 31;
                const int cp  = (32 + c32) ^ (row & 7);
                *(bf16x8*)&Alds[0][(size_t)row * 512 + cp * 8] = tmp[i];
            }
        }

        // W1/W3 polled by different waves IN PARALLEL; B1 joins them.
        if (v == 2 && j > 0 && lane == 0) spin_ge(done_prod, 4u * (unsigned)(t + 1));
        if (v == 3 && j < NL - 1 && t >= 2 && lane == 0) spin_ge(done_cons, 4u * (unsigned)(t - 1));
        __syncthreads();   // B1: h staged + producer published + consumer drained

        // acc = bias; Whh @ h_prev (register-resident weights)
        f32x4 acc[4][4];
#pragma unroll
        for (int g = 0; g < 4; ++g) {
            const float bb = biasg[g];
            const f32x4 bv = {bb, bb, bb, bb};
#pragma unroll
            for (int bs = 0; bs < 4; ++bs) acc[bs][g] = bv;
        }
#pragma unroll
        for (int ch = 0; ch < 8; ++ch) {
#pragma unroll
            for (int bs = 0; bs < 4; ++bs) {
                const int rowA = bs * 16 + m;
                const int cp = (32 + ch * 4 + q) ^ (rowA & 7);
                const bf16x8 af = *(const bf16x8*)&Alds[rowA][cp * 8];
#pragma unroll
                for (int g = 0; g < 4; ++g)
                    acc[bs][g] = __builtin_amdgcn_mfma_f32_16x16x32_bf16(
                        af, wfhh[ch][g], acc[bs][g], 0, 0, 0);
            }
        }

        // stage cur into Alds lo half (producer already verified at B1)
        if (j == 0) {
            const float* xt = x + (size_t)t * BH;
#pragma unroll
            for (int i = 0; i < 8; ++i) {
                const int row = i * 8 + v * 2 + (lane >> 5);
                const int c32 = lane & 31;
                const int cp  = c32 ^ (row & 7);
                const float4* p = (const float4*)(xt + (size_t)(b0 + row) * HID + c32 * 8);
                const float4 u0 = p[0];
                const float4 u1 = p[1];
                bf16x8 vv;
                vv[0] = (__bf16)u0.x; vv[1] = (__bf16)u0.y;
                vv[2] = (__bf16)u0.z; vv[3] = (__bf16)u0.w;
                vv[4] = (__bf16)u1.x; vv[5] = (__bf16)u1.y;
                vv[6] = (__bf16)u1.z; vv[7] = (__bf16)u1.w;
                *(bf16x8*)&Alds[0][(size_t)row * 512 + cp * 8] = vv;
            }
        } else {
            const __bf16* ct = cbuf + (size_t)((j - 1) * 2 + par) * BH;
            bf16x8 tmp[8];
#pragma unroll
            for (int i = 0; i < 8; ++i) {
                const int row = i * 8 + v * 2 + (lane >> 5);
                const int c32 = lane & 31;
                ldg_coh(tmp[i], ct + (size_t)(b0 + row) * HID + c32 * 8);
            }
            wait_vm0();
#pragma unroll
            for (int i = 0; i < 8; ++i) {
                const int row = i * 8 + v * 2 + (lane >> 5);
                const int c32 = lane & 31;
                const int cp  = c32 ^ (row & 7);
                *(bf16x8*)&Alds[0][(size_t)row * 512 + cp * 8] = tmp[i];
            }
        }
        __syncthreads();   // B2

        // Wih @ cur (register-resident weights — zero memory traffic)
#pragma unroll
        for (int ch = 0; ch < 8; ++ch) {
#pragma unroll
            for (int bs = 0; bs < 4; ++bs) {
                const int rowA = bs * 16 + m;
                const int cp = (ch * 4 + q) ^ (rowA & 7);
                const bf16x8 af = *(const bf16x8*)&Alds[rowA][cp * 8];
#pragma unroll
                for (int g = 0; g < 4; ++g)
                    acc[bs][g] = __builtin_amdgcn_mfma_f32_16x16x32_bf16(
                        af, wfih[ch][g], acc[bs][g], 0, 0, 0);
            }
        }

        // epilogue
        __bf16* cnext = (j < NL - 1) ? (cbuf + (size_t)(j * 2 + par) * BH) : (__bf16*)0;
#pragma unroll
        for (int bs = 0; bs < 4; ++bs) {
#pragma unroll
            for (int r = 0; r < 4; ++r) {
                const int b = b0 + bs * 16 + q * 4 + r;
                const float ii = fsigmoid(acc[bs][0][r]);
                const float ff = fsigmoid(acc[bs][1][r]);
                const float tg = ftanh(acc[bs][2][r]);
                const float oo = fsigmoid(acc[bs][3][r]);
                const float cn = ff * c_state[bs][r] + ii * tg;   // c' -> next layer input
                const float hn = oo * ftanh(cn);                   // h' -> recurrent operand
                c_state[bs][r] = cn;
                hout[(size_t)b * HID + hw] = (__bf16)hn;           // intra-XCD: plain -> L2
                if (j < NL - 1) {
                    stg_coh_b16(cnext + (size_t)b * HID + hw, (__bf16)cn);  // cross-XCD WT
                } else if (t == SEQ - 1) {
                    out[(size_t)b * HID + hw] = cn;                // fp32, kernel-end flush
                }
            }
        }

        wait_vm0();        // h/c stores at their coherence level
        __syncthreads();   // B3: all waves drained
        if (tid == 0)
            __hip_atomic_fetch_add(done_self, 1u, __ATOMIC_RELAXED,
                                   __HIP_MEMORY_SCOPE_AGENT);
    }
}

extern "C" void kernel_launch(void* const* d_in, const int* in_sizes, int n_in,
                              void* d_out, int out_size, void* d_ws, size_t ws_size,
                              hipStream_t stream)
{
    (void)in_sizes; (void)n_in; (void)out_size; (void)ws_size;
    const float* x   = (const float*)d_in[0];
    const float* Wih = (const float*)d_in[1];
    const float* Whh = (const float*)d_in[2];
    const float* bih = (const float*)d_in[3];
    const float* bhh = (const float*)d_in[4];
    float* out = (float*)d_out;

    char* ws = (char*)d_ws;
    __bf16* wih_bf = (__bf16*)(ws);
    __bf16* whh_bf = (__bf16*)(ws + 5242880);
    float*  biasc  = (float*) (ws + 10485760);
    __bf16* scb    = (__bf16*)(ws + 10526720);
    __bf16* cbuf   = (__bf16*)(ws + 13148160);
    unsigned int* done = (unsigned int*)(ws + 15507456);

    lstm_prep<<<dim3(1024), dim3(256), 0, stream>>>(
        Wih, Whh, bih, bhh, wih_bf, whh_bf, biasc, scb, done);
    lstm_main<<<dim3(NBLK), dim3(256), 0, stream>>>(
        x, wih_bf, whh_bf, biasc, scb, cbuf, out, done);
}